// Round 1
// baseline (70472.168 us; speedup 1.0000x reference)
//
#include <hip/hip_runtime.h>

#define BB 256     // batch
#define SS 128     // encoder seq len
#define FDIM 128   // input feature
#define HH 512     // hidden
#define H4 2048    // 4*H
#define TDEC 128   // decode steps
#define SOS_TOK 128

__device__ __forceinline__ float sigf(float x){ return 1.0f/(1.0f+__expf(-x)); }
__device__ __forceinline__ float tanh_f(float x){ return 1.0f - 2.0f/(__expf(2.0f*x)+1.0f); }

// ---------------- repack: interleave gates (i,f,g,o) per hidden unit ----------------
// dst[(q*4+g)*dstStride + dstOff + k] = src[(g*512+q)*K + k]
__global__ void repack_w(float* __restrict__ dst, const float* __restrict__ src,
                         int K, int dstStride, int dstOff){
    int id = blockIdx.x*256 + threadIdx.x;
    int K4 = K >> 2;
    int total = 512*4*K4;
    if (id >= total) return;
    int k4 = id % K4; int rest = id / K4; int g = rest & 3; int q = rest >> 2;
    float4 v = *(const float4*)&src[(size_t)(g*512+q)*K + (size_t)k4*4];
    *(float4*)&dst[(size_t)(q*4+g)*dstStride + dstOff + (size_t)k4*4] = v;
}

__global__ void repack_b(float* __restrict__ dst, const float* __restrict__ src){
    int id = blockIdx.x*256 + threadIdx.x;
    if (id >= 2048) return;
    int g = id & 3, q = id >> 2;
    dst[id] = src[g*512 + q];
}

__global__ void init_tok(int* __restrict__ tok){
    tok[threadIdx.x] = SOS_TOK;
}

__global__ void gather_emb(float* __restrict__ xemb, const float* __restrict__ emb,
                           const int* __restrict__ tok){
    int id = blockIdx.x*256 + threadIdx.x;        // B*H/4 = 32768 float4s
    int b = id >> 7; int k4 = id & 127;
    float4 v = *(const float4*)&emb[(size_t)tok[b]*HH + (size_t)k4*4];
    *(float4*)&xemb[(size_t)b*HH + (size_t)k4*4] = v;
}

// ---------------- big GEMM: C = A @ W^T + bias ----------------
// A row r addr = A + (r&255)*sB + (r>>8)*sT  (r = ti*256 + b)
// C row r addr = C + (r&255)*oB + (r>>8)*oT
// 128x128 tile, TK=16, 256 thr, 8x8 micro
__global__ __launch_bounds__(256) void gemm_big(
    const float* __restrict__ A, size_t sB_, size_t sT_, int K,
    const float* __restrict__ W, const float* __restrict__ bias,
    float* __restrict__ C, size_t oB_, size_t oT_)
{
    __shared__ __align__(16) float As[16][132];
    __shared__ __align__(16) float Ws[16][132];
    const int tid = threadIdx.x;
    const int row0 = blockIdx.y * 128, col0 = blockIdx.x * 128;
    const int lr = tid >> 2;
    const int lk = (tid & 3) << 2;
    const int tx = tid & 15, ty = tid >> 4;
    const int mrow = ty*8, mcol = tx*8;
    float acc[8][8];
    #pragma unroll
    for (int i=0;i<8;i++)
        #pragma unroll
        for (int j=0;j<8;j++) acc[i][j]=0.0f;

    float4 ra0, ra1, rw0, rw1;
    {
        int r0 = row0 + lr, r1 = row0 + lr + 64;
        ra0 = *(const float4*)(A + (size_t)(r0&255)*sB_ + (size_t)(r0>>8)*sT_ + lk);
        ra1 = *(const float4*)(A + (size_t)(r1&255)*sB_ + (size_t)(r1>>8)*sT_ + lk);
        rw0 = *(const float4*)(W + (size_t)(col0+lr)*K + lk);
        rw1 = *(const float4*)(W + (size_t)(col0+lr+64)*K + lk);
    }
    for (int kt=0; kt<K; kt+=16){
        As[lk+0][lr]=ra0.x; As[lk+1][lr]=ra0.y; As[lk+2][lr]=ra0.z; As[lk+3][lr]=ra0.w;
        As[lk+0][lr+64]=ra1.x; As[lk+1][lr+64]=ra1.y; As[lk+2][lr+64]=ra1.z; As[lk+3][lr+64]=ra1.w;
        Ws[lk+0][lr]=rw0.x; Ws[lk+1][lr]=rw0.y; Ws[lk+2][lr]=rw0.z; Ws[lk+3][lr]=rw0.w;
        Ws[lk+0][lr+64]=rw1.x; Ws[lk+1][lr+64]=rw1.y; Ws[lk+2][lr+64]=rw1.z; Ws[lk+3][lr+64]=rw1.w;
        __syncthreads();
        if (kt+16 < K){
            int kn = kt+16+lk;
            int r0 = row0 + lr, r1 = row0 + lr + 64;
            ra0 = *(const float4*)(A + (size_t)(r0&255)*sB_ + (size_t)(r0>>8)*sT_ + kn);
            ra1 = *(const float4*)(A + (size_t)(r1&255)*sB_ + (size_t)(r1>>8)*sT_ + kn);
            rw0 = *(const float4*)(W + (size_t)(col0+lr)*K + kn);
            rw1 = *(const float4*)(W + (size_t)(col0+lr+64)*K + kn);
        }
        #pragma unroll
        for (int kk=0; kk<16; ++kk){
            float av[8], wv[8];
            *(float4*)&av[0] = *(const float4*)&As[kk][mrow];
            *(float4*)&av[4] = *(const float4*)&As[kk][mrow+4];
            *(float4*)&wv[0] = *(const float4*)&Ws[kk][mcol];
            *(float4*)&wv[4] = *(const float4*)&Ws[kk][mcol+4];
            #pragma unroll
            for (int i=0;i<8;i++)
                #pragma unroll
                for (int j=0;j<8;j++)
                    acc[i][j] = fmaf(av[i], wv[j], acc[i][j]);
        }
        __syncthreads();
    }
    float bv[8];
    #pragma unroll
    for (int j=0;j<8;j++) bv[j] = bias ? bias[col0+mcol+j] : 0.0f;
    #pragma unroll
    for (int i=0;i<8;i++){
        int r = row0 + mrow + i;
        float* cp = C + (size_t)(r&255)*oB_ + (size_t)(r>>8)*oT_ + col0 + mcol;
        float4 o0 = make_float4(acc[i][0]+bv[0], acc[i][1]+bv[1], acc[i][2]+bv[2], acc[i][3]+bv[3]);
        float4 o1 = make_float4(acc[i][4]+bv[4], acc[i][5]+bv[5], acc[i][6]+bv[6], acc[i][7]+bv[7]);
        *(float4*)cp = o0; *(float4*)(cp+4) = o1;
    }
}

// ---------------- small GEMM (M=256) with up to 3 A-segments; MODE 0=plain(+relu), 1=fused LSTM cell ----------------
// 32x64 tile, TK=16, 256 thr, 2x4 micro (4-col microtile == one gate quadruple for MODE 1)
template<int MODE>
__global__ __launch_bounds__(256) void gemm_small(
    const float* __restrict__ A0, const float* __restrict__ A1, const float* __restrict__ A2,
    int lsw, int K,
    const float* __restrict__ W, const float* __restrict__ bias,
    const float* __restrict__ xz,
    float* __restrict__ C, int ldc,
    float* __restrict__ h_out, float* __restrict__ c_io,
    int relu)
{
    __shared__ __align__(16) float As[16][36];
    __shared__ __align__(16) float Ws[16][68];
    const int tid = threadIdx.x;
    const int row0 = blockIdx.y * 32, col0 = blockIdx.x * 64;
    const int lr = tid >> 2;              // A: 0..31 (tid<128), W: 0..63
    const int lk = (tid & 3) << 2;
    const int tx = tid & 15, ty = tid >> 4;
    const int segw = 1 << lsw;
    float acc[2][4];
    acc[0][0]=acc[0][1]=acc[0][2]=acc[0][3]=0.f;
    acc[1][0]=acc[1][1]=acc[1][2]=acc[1][3]=0.f;

    auto ldA = [&](int kt)->float4{
        int k = kt + lk; int seg = k >> lsw; int ko = k & (segw-1);
        const float* sp = (seg==0)? A0 : ((seg==1)? A1 : A2);
        return *(const float4*)(sp + (size_t)(row0+lr)*segw + ko);
    };
    auto ldW = [&](int kt)->float4{
        return *(const float4*)(W + (size_t)(col0+lr)*K + kt + lk);
    };
    float4 ra = make_float4(0,0,0,0), rw;
    if (tid < 128) ra = ldA(0);
    rw = ldW(0);
    for (int kt=0; kt<K; kt+=16){
        if (tid < 128){ As[lk+0][lr]=ra.x; As[lk+1][lr]=ra.y; As[lk+2][lr]=ra.z; As[lk+3][lr]=ra.w; }
        Ws[lk+0][lr]=rw.x; Ws[lk+1][lr]=rw.y; Ws[lk+2][lr]=rw.z; Ws[lk+3][lr]=rw.w;
        __syncthreads();
        float4 na = make_float4(0,0,0,0), nw = make_float4(0,0,0,0);
        if (kt+16 < K){
            if (tid < 128) na = ldA(kt+16);
            nw = ldW(kt+16);
        }
        #pragma unroll
        for (int kk=0; kk<16; ++kk){
            float2 av = *(const float2*)&As[kk][ty*2];
            float4 wv = *(const float4*)&Ws[kk][tx*4];
            acc[0][0]=fmaf(av.x,wv.x,acc[0][0]); acc[0][1]=fmaf(av.x,wv.y,acc[0][1]);
            acc[0][2]=fmaf(av.x,wv.z,acc[0][2]); acc[0][3]=fmaf(av.x,wv.w,acc[0][3]);
            acc[1][0]=fmaf(av.y,wv.x,acc[1][0]); acc[1][1]=fmaf(av.y,wv.y,acc[1][1]);
            acc[1][2]=fmaf(av.y,wv.z,acc[1][2]); acc[1][3]=fmaf(av.y,wv.w,acc[1][3]);
        }
        __syncthreads();
        ra = na; rw = nw;
    }
    const int gr0 = row0 + ty*2;
    const int gc  = col0 + tx*4;
    if (MODE == 0){
        #pragma unroll
        for (int r=0;r<2;r++){
            #pragma unroll
            for (int j=0;j<4;j++){
                float v = acc[r][j] + (bias ? bias[gc+j] : 0.0f);
                if (relu) v = fmaxf(v, 0.0f);
                C[(size_t)(gr0+r)*ldc + gc + j] = v;
            }
        }
    } else {
        const int q = gc >> 2;
        #pragma unroll
        for (int r=0;r<2;r++){
            int b_ = gr0 + r;
            float a0,a1,a2,a3;
            if (xz){
                float4 v = *(const float4*)&xz[(size_t)b_*H4 + gc];
                a0=v.x; a1=v.y; a2=v.z; a3=v.w;
            } else {
                float4 v = *(const float4*)&bias[gc];
                a0=v.x; a1=v.y; a2=v.z; a3=v.w;
            }
            float iv = acc[r][0]+a0, fv = acc[r][1]+a1, gv = acc[r][2]+a2, ov = acc[r][3]+a3;
            float co = c_io[(size_t)b_*HH + q];
            float cn = sigf(fv)*co + sigf(iv)*tanh_f(gv);
            float hn = sigf(ov)*tanh_f(cn);
            c_io[(size_t)b_*HH + q] = cn;
            h_out[(size_t)b_*HH + q] = hn;
        }
    }
}

// ---------------- fused attention: scores(tanh)+softmax+context, one block per batch elem ----------------
__global__ __launch_bounds__(256) void attn_kernel(
    const float* __restrict__ ht,   // [B,256]
    const float* __restrict__ ot,   // [B,S,256]
    const float* __restrict__ enc,  // [S,B,H]
    const float* __restrict__ fc3,  // [256]
    float* __restrict__ ctx)        // [B,H]
{
    __shared__ float hts[256], f3s[256], wsm[SS];
    const int b = blockIdx.x, tid = threadIdx.x;
    hts[tid] = ht[(size_t)b*256 + tid];
    f3s[tid] = fc3[tid];
    __syncthreads();
    const int wave = tid >> 6, lane = tid & 63;
    const float* otb = ot + (size_t)b*SS*256;
    for (int i=0;i<32;i++){
        int s = wave*32 + i;
        float4 o = *(const float4*)&otb[(size_t)s*256 + lane*4];
        int d0 = lane*4;
        float v = f3s[d0+0]*tanh_f(o.x + hts[d0+0])
                + f3s[d0+1]*tanh_f(o.y + hts[d0+1])
                + f3s[d0+2]*tanh_f(o.z + hts[d0+2])
                + f3s[d0+3]*tanh_f(o.w + hts[d0+3]);
        #pragma unroll
        for (int off=32; off; off>>=1) v += __shfl_xor(v, off);
        if (lane == 0) wsm[s] = v;
    }
    __syncthreads();
    if (tid < 64){
        float v0 = wsm[tid], v1 = wsm[tid+64];
        float m = fmaxf(v0, v1);
        #pragma unroll
        for (int off=32; off; off>>=1) m = fmaxf(m, __shfl_xor(m, off));
        float e0 = __expf(v0 - m), e1 = __expf(v1 - m);
        float ss = e0 + e1;
        #pragma unroll
        for (int off=32; off; off>>=1) ss += __shfl_xor(ss, off);
        float inv = 1.0f/ss;
        wsm[tid] = e0*inv; wsm[tid+64] = e1*inv;
    }
    __syncthreads();
    float a0=0.f, a1=0.f;
    const float* eb = enc + (size_t)b*HH;
    #pragma unroll 8
    for (int s=0;s<SS;s++){
        float w = wsm[s];
        const float* e = eb + (size_t)s*BB*HH;
        a0 = fmaf(w, e[tid],      a0);
        a1 = fmaf(w, e[tid+256],  a1);
    }
    ctx[(size_t)b*HH + tid]      = a0;
    ctx[(size_t)b*HH + tid+256]  = a1;
}

// ---------------- argmax over 128 logits per row (first-index tie-break) ----------------
__global__ __launch_bounds__(64) void argmax_kernel(const float* __restrict__ logits, int* __restrict__ tok){
    const int b = blockIdx.x, lane = threadIdx.x;
    const float* r = logits + (size_t)b*128;
    float v0 = r[lane], v1 = r[lane+64];
    float bv; int bi;
    if (v1 > v0){ bv = v1; bi = lane+64; } else { bv = v0; bi = lane; }
    #pragma unroll
    for (int off=32; off; off>>=1){
        float ov = __shfl_xor(bv, off);
        int   oi = __shfl_xor(bi, off);
        if (ov > bv || (ov == bv && oi < bi)){ bv = ov; bi = oi; }
    }
    if (lane == 0) tok[b] = bi;
}

extern "C" void kernel_launch(void* const* d_in, const int* in_sizes, int n_in,
                              void* d_out, int out_size, void* d_ws, size_t ws_size,
                              hipStream_t stream)
{
    (void)in_sizes; (void)n_in; (void)out_size;
    const float* l2      = (const float*)d_in[0];
    const float* e_wih[3] = {(const float*)d_in[1],(const float*)d_in[4],(const float*)d_in[7]};
    const float* e_whh[3] = {(const float*)d_in[2],(const float*)d_in[5],(const float*)d_in[8]};
    const float* e_b[3]   = {(const float*)d_in[3],(const float*)d_in[6],(const float*)d_in[9]};
    const float* d_wih[3] = {(const float*)d_in[10],(const float*)d_in[13],(const float*)d_in[16]};
    const float* d_whh[3] = {(const float*)d_in[11],(const float*)d_in[14],(const float*)d_in[17]};
    const float* d_b[3]   = {(const float*)d_in[12],(const float*)d_in[15],(const float*)d_in[18]};
    const float* emb   = (const float*)d_in[19];
    const float* fc1_w = (const float*)d_in[20]; const float* fc1_b = (const float*)d_in[21];
    const float* fc2_w = (const float*)d_in[22]; const float* fc2_b = (const float*)d_in[23];
    const float* fc3_w = (const float*)d_in[24];
    const float* w1 = (const float*)d_in[25]; const float* b1 = (const float*)d_in[26];
    const float* w2 = (const float*)d_in[27]; const float* b2 = (const float*)d_in[28];
    const float* w3 = (const float*)d_in[29]; const float* b3 = (const float*)d_in[30];
    float* out = (float*)d_out;

    float* base = (float*)d_ws;
    size_t off = 0;
    auto alloc = [&](size_t n)->float*{ float* r = base + off; off = (off + n + 63) & ~(size_t)63; return r; };

    float* wr_ih[3]; float* wr_hh[3]; float* br_e[3];
    wr_ih[0] = alloc(2048*128);
    wr_ih[1] = alloc(2048*512);
    wr_ih[2] = alloc(2048*512);
    for (int l=0;l<3;l++) wr_hh[l] = alloc(2048*512);
    for (int l=0;l<3;l++) br_e[l]  = alloc(2048);
    float* wr_d[3]; float* br_d[3];
    wr_d[0] = alloc(2048*1536);
    wr_d[1] = alloc(2048*1024);
    wr_d[2] = alloc(2048*1024);
    for (int l=0;l<3;l++) br_d[l] = alloc(2048);

    float* seq  = alloc((size_t)SS*BB*HH);     // encoder h sequence (reused across layers; final = enc_outs)
    float* ot   = alloc((size_t)BB*SS*256);    // [b][s][256]
    float* zbuf = alloc((size_t)BB*HH);
    float* cbuf[3]; for (int l=0;l<3;l++) cbuf[l] = alloc((size_t)BB*HH);
    float* hbuf[3][2];
    for (int l=0;l<3;l++) for (int p=0;p<2;p++) hbuf[l][p] = alloc((size_t)BB*HH);
    float* xemb = alloc((size_t)BB*HH);
    float* ctx  = alloc((size_t)BB*HH);
    float* ht   = alloc((size_t)BB*256);
    float* hdd1 = alloc((size_t)BB*512);
    float* hdd2 = alloc((size_t)BB*256);
    int*   tok  = (int*)alloc(256);

    // XZ chunk buffer sized to whatever workspace remains
    size_t remain = (ws_size/4 > off) ? (ws_size/4 - off) : 0;
    int CHUNK = 4;
    if      (remain >= (size_t)32*BB*H4) CHUNK = 32;
    else if (remain >= (size_t)16*BB*H4) CHUNK = 16;
    else if (remain >= (size_t) 8*BB*H4) CHUNK = 8;
    float* xz = base + off;

    // ---- repack weights (gate-interleaved) ----
    auto rp = [&](float* dst, const float* src, int K, int stride, int offc){
        int total = 512*4*(K/4);
        hipLaunchKernelGGL(repack_w, dim3((total+255)/256), dim3(256), 0, stream, dst, src, K, stride, offc);
    };
    rp(wr_ih[0], e_wih[0], 128, 128, 0);
    rp(wr_ih[1], e_wih[1], 512, 512, 0);
    rp(wr_ih[2], e_wih[2], 512, 512, 0);
    for (int l=0;l<3;l++) rp(wr_hh[l], e_whh[l], 512, 512, 0);
    for (int l=0;l<3;l++) hipLaunchKernelGGL(repack_b, dim3(8), dim3(256), 0, stream, br_e[l], e_b[l]);
    rp(wr_d[0], d_wih[0], 1024, 1536, 0);
    rp(wr_d[0], d_whh[0],  512, 1536, 1024);
    rp(wr_d[1], d_wih[1],  512, 1024, 0);
    rp(wr_d[1], d_whh[1],  512, 1024, 512);
    rp(wr_d[2], d_wih[2],  512, 1024, 0);
    rp(wr_d[2], d_whh[2],  512, 1024, 512);
    for (int l=0;l<3;l++) hipLaunchKernelGGL(repack_b, dim3(8), dim3(256), 0, stream, br_d[l], d_b[l]);

    hipMemsetAsync(zbuf, 0, (size_t)BB*HH*4, stream);
    for (int l=0;l<3;l++) hipMemsetAsync(cbuf[l], 0, (size_t)BB*HH*4, stream);
    hipMemsetAsync(ctx, 0, (size_t)BB*HH*4, stream);

    // ---- encoder: 3 layers, chunked input-transform + sequential fused LSTM steps ----
    for (int l=0;l<3;l++){
        const int Kih = (l==0)? FDIM : HH;
        const int nch = SS / CHUNK;
        for (int tc=0; tc<nch; tc++){
            const float* Abase; size_t sBs, sTs;
            if (l == 0){ Abase = l2 + (size_t)tc*CHUNK*FDIM; sBs = (size_t)SS*FDIM; sTs = FDIM; }
            else       { Abase = seq + (size_t)tc*CHUNK*BB*HH; sBs = HH; sTs = (size_t)BB*HH; }
            hipLaunchKernelGGL(gemm_big, dim3(H4/128, CHUNK*BB/128), dim3(256), 0, stream,
                               Abase, sBs, sTs, Kih, wr_ih[l], br_e[l],
                               xz, (size_t)H4, (size_t)BB*H4);
            for (int ti=0; ti<CHUNK; ti++){
                int t = tc*CHUNK + ti;
                const float* hp = (t==0) ? zbuf : seq + (size_t)(t-1)*BB*HH;
                hipLaunchKernelGGL((gemm_small<1>), dim3(H4/64, BB/32), dim3(256), 0, stream,
                                   hp, (const float*)nullptr, (const float*)nullptr, 9, HH,
                                   wr_hh[l], (const float*)nullptr, xz + (size_t)ti*BB*H4,
                                   (float*)nullptr, 0,
                                   seq + (size_t)t*BB*HH, cbuf[l], 0);
            }
        }
        hipMemcpyAsync(hbuf[l][0], seq + (size_t)(SS-1)*BB*HH, (size_t)BB*HH*4,
                       hipMemcpyDeviceToDevice, stream);
    }

    // ---- ot = enc_outs @ fc2^T + fc2_b, stored [b][s][256] ----
    hipLaunchKernelGGL(gemm_big, dim3(256/128, SS*BB/128), dim3(256), 0, stream,
                       seq, (size_t)HH, (size_t)BB*HH, HH, fc2_w, fc2_b,
                       ot, (size_t)SS*256, (size_t)256);

    // ---- decoder ----
    hipLaunchKernelGGL(init_tok, dim3(1), dim3(256), 0, stream, tok);
    for (int t=0; t<TDEC; t++){
        const int p = t & 1;
        hipLaunchKernelGGL(gather_emb, dim3((BB*HH/4)/256), dim3(256), 0, stream, xemb, emb, tok);
        // LSTM layer 0: [emb | ctx | h0_prev] (K=1536)
        hipLaunchKernelGGL((gemm_small<1>), dim3(H4/64, BB/32), dim3(256), 0, stream,
                           xemb, ctx, hbuf[0][p], 9, 3*HH, wr_d[0], br_d[0], (const float*)nullptr,
                           (float*)nullptr, 0, hbuf[0][p^1], cbuf[0], 0);
        // LSTM layer 1: [h0_new | h1_prev] (K=1024)
        hipLaunchKernelGGL((gemm_small<1>), dim3(H4/64, BB/32), dim3(256), 0, stream,
                           hbuf[0][p^1], hbuf[1][p], (const float*)nullptr, 9, 2*HH, wr_d[1], br_d[1], (const float*)nullptr,
                           (float*)nullptr, 0, hbuf[1][p^1], cbuf[1], 0);
        // LSTM layer 2
        hipLaunchKernelGGL((gemm_small<1>), dim3(H4/64, BB/32), dim3(256), 0, stream,
                           hbuf[1][p^1], hbuf[2][p], (const float*)nullptr, 9, 2*HH, wr_d[2], br_d[2], (const float*)nullptr,
                           (float*)nullptr, 0, hbuf[2][p^1], cbuf[2], 0);
        // fc1: ht = h2 @ fc1^T + b
        hipLaunchKernelGGL((gemm_small<0>), dim3(256/64, BB/32), dim3(256), 0, stream,
                           hbuf[2][p^1], (const float*)nullptr, (const float*)nullptr, 9, HH,
                           fc1_w, fc1_b, (const float*)nullptr,
                           ht, 256, (float*)nullptr, (float*)nullptr, 0);
        // attention -> ctx
        hipLaunchKernelGGL(attn_kernel, dim3(BB), dim3(256), 0, stream, ht, ot, seq, fc3_w, ctx);
        // MLP
        hipLaunchKernelGGL((gemm_small<0>), dim3(512/64, BB/32), dim3(256), 0, stream,
                           hbuf[2][p^1], ctx, (const float*)nullptr, 9, 2*HH,
                           w1, b1, (const float*)nullptr,
                           hdd1, 512, (float*)nullptr, (float*)nullptr, 1);
        hipLaunchKernelGGL((gemm_small<0>), dim3(256/64, BB/32), dim3(256), 0, stream,
                           hdd1, (const float*)nullptr, (const float*)nullptr, 9, 512,
                           w2, b2, (const float*)nullptr,
                           hdd2, 256, (float*)nullptr, (float*)nullptr, 1);
        hipLaunchKernelGGL((gemm_small<0>), dim3(128/64, BB/32), dim3(256), 0, stream,
                           hdd2, (const float*)nullptr, (const float*)nullptr, 8, 256,
                           w3, b3, (const float*)nullptr,
                           out + (size_t)t*BB*128, 128, (float*)nullptr, (float*)nullptr, 0);
        hipLaunchKernelGGL(argmax_kernel, dim3(BB), dim3(64), 0, stream, out + (size_t)t*BB*128, tok);
    }
}

// Round 2
// 27710.608 us; speedup vs baseline: 2.5431x; 2.5431x over previous
//
#include <hip/hip_runtime.h>

#define BB 256     // batch
#define SS 128     // encoder seq len
#define FDIM 128   // input feature
#define HH 512     // hidden
#define H4 2048    // 4*H
#define TDEC 128   // decode steps
#define SOS_TOK 128

typedef short short8 __attribute__((ext_vector_type(8)));
typedef float f32x4 __attribute__((ext_vector_type(4)));

__device__ __forceinline__ float sigf(float x){ return 1.0f/(1.0f+__expf(-x)); }
__device__ __forceinline__ float tanh_f(float x){ return 1.0f - 2.0f/(__expf(2.0f*x)+1.0f); }

// round-to-nearest-even bf16 3-way split: x ~= hi + mid + lo (24 mantissa bits)
__device__ __forceinline__ void split3(float x, unsigned& h, unsigned& m, unsigned& l){
    union { float f; unsigned u; } a; a.f = x;
    h = (a.u + 0x7fffu + ((a.u>>16)&1u)) >> 16;
    union { unsigned u; float f; } hf; hf.u = h << 16;
    float r1 = x - hf.f;
    union { float f; unsigned u; } b; b.f = r1;
    m = (b.u + 0x7fffu + ((b.u>>16)&1u)) >> 16;
    union { unsigned u; float f; } mf; mf.u = m << 16;
    float r2 = r1 - mf.f;
    union { float f; unsigned u; } c; c.f = r2;
    l = (c.u + 0x7fffu + ((c.u>>16)&1u)) >> 16;
}

__device__ __forceinline__ void splitw8(float4 v, uint2& H, uint2& M, uint2& L){
    unsigned h0,m0,l0,h1,m1,l1,h2,m2,l2,h3,m3,l3;
    split3(v.x,h0,m0,l0); split3(v.y,h1,m1,l1); split3(v.z,h2,m2,l2); split3(v.w,h3,m3,l3);
    H.x = h0 | (h1<<16); H.y = h2 | (h3<<16);
    M.x = m0 | (m1<<16); M.y = m2 | (m3<<16);
    L.x = l0 | (l1<<16); L.y = l2 | (l3<<16);
}

// ---------------- weight split: fp32 [N][K] (opt gate-interleave, opt 2-src K-concat)
// -> 3 bf16 planes, k-panel layout [K/32][N][32] with 16B-part XOR swizzle
__global__ void split_w(const float* __restrict__ srcA, int KA,
                        const float* __restrict__ srcB, int KB, int ilv,
                        unsigned short* __restrict__ ph, unsigned short* __restrict__ pm,
                        unsigned short* __restrict__ pl, int N){
    int k = blockIdx.x*128 + threadIdx.x;
    int n = blockIdx.y;
    int K = KA + KB;
    if (k >= K) return;
    int row = ilv ? ((n&3)*512 + (n>>2)) : n;
    float w = (k < KA) ? srcA[(size_t)row*KA + k] : srcB[(size_t)row*KB + (k-KA)];
    unsigned h,m,l; split3(w,h,m,l);
    size_t off = (size_t)(k>>5)*((size_t)N*32) + (size_t)n*32
               + ((((k>>3)&3) ^ (n&3))<<3) + (k&7);
    ph[off]=(unsigned short)h; pm[off]=(unsigned short)m; pl[off]=(unsigned short)l;
}

__global__ void repack_b(float* __restrict__ dst, const float* __restrict__ src){
    int id = blockIdx.x*256 + threadIdx.x;
    if (id >= 2048) return;
    int g = id & 3, q = id >> 2;
    dst[id] = src[g*512 + q];
}

__global__ void init_tok(int* __restrict__ tok){ tok[threadIdx.x] = SOS_TOK; }

// ---------------- unified MFMA GEMM: C = A @ W^T (fp32 via 3-way bf16 split, 6 products)
// WG: 256 thr = 4 waves (2x2), wave tile 32x32 (2x2 frags of 16x16x32), WG tile 64x64.
// A: fp32, up to 3 K-segments (A0 general strides + opt tok row-indirection; A1/A2 stride 512).
// W: prebuilt 3 bf16 planes [Ktot/32][Nld][32], swizzled.
// MODE 0: out = acc + bias (+relu), fp32, row addr (r&255)*oB+(r>>8)*oT
// MODE 1: zpart[blockIdx.z][r][Nld] = acc (K-split partials)
// MODE 2: encoder fused LSTM cell: z = acc + xz; gates via shfl_xor; writes c_io, seqo
#define MM6(AH,AM,AL,BH,BM,BL,C) \
  C = __builtin_amdgcn_mfma_f32_16x16x32_bf16(AH,BH,C,0,0,0); \
  C = __builtin_amdgcn_mfma_f32_16x16x32_bf16(AH,BM,C,0,0,0); \
  C = __builtin_amdgcn_mfma_f32_16x16x32_bf16(AM,BH,C,0,0,0); \
  C = __builtin_amdgcn_mfma_f32_16x16x32_bf16(AH,BL,C,0,0,0); \
  C = __builtin_amdgcn_mfma_f32_16x16x32_bf16(AL,BH,C,0,0,0); \
  C = __builtin_amdgcn_mfma_f32_16x16x32_bf16(AM,BM,C,0,0,0);

template<int MODE>
__global__ __launch_bounds__(256) void mg(
    const float* __restrict__ A0, long a0B, long a0T,
    const float* __restrict__ A1, const float* __restrict__ A2,
    const int* __restrict__ tok, int ksh,
    const unsigned short* __restrict__ Wh, const unsigned short* __restrict__ Wm,
    const unsigned short* __restrict__ Wl, int Nld,
    int Kc, int Mrows,
    const float* __restrict__ bias, int relu,
    float* __restrict__ out, long oB, long oT,
    const float* __restrict__ xz, float* __restrict__ c_io, float* __restrict__ seqo)
{
    __shared__ __align__(16) unsigned short sA[2][3][2048];
    __shared__ __align__(16) unsigned short sW[2][3][2048];
    const int tid = threadIdx.x;
    const int row0 = blockIdx.y * 64, col0 = blockIdx.x * 64;
    const int kz = blockIdx.z * Kc;
    const int nk = Kc >> 5;

    f32x4 acc[2][2];
    acc[0][0] = (f32x4){0.f,0.f,0.f,0.f}; acc[0][1] = (f32x4){0.f,0.f,0.f,0.f};
    acc[1][0] = (f32x4){0.f,0.f,0.f,0.f}; acc[1][1] = (f32x4){0.f,0.f,0.f,0.f};

    // staging thread mapping: row sr (0..63), quarter q4 (2 float4 per thread)
    const int sr = tid >> 2, q4 = tid & 3;
    const int gr = row0 + sr;
    long ro0;
    if (tok){ int rr = tok[gr & 255]; ro0 = (long)rr * a0B; }
    else ro0 = (long)(gr & 255)*a0B + (long)(gr >> 8)*a0T;
    const long ro1 = (long)gr * 512;
    const size_t wbase = (size_t)col0*32 + (size_t)tid*8;
    const int swz = sr & 3;
    const int b0 = sr*32 + (q4 & 1)*4;
    const int p0s = ((q4>>1) ^ swz) << 3;
    const int p1s = ((2 + (q4>>1)) ^ swz) << 3;

    float4 va0, va1; uint4 vw0, vw1, vw2;

    auto issue = [&](int kt){
        int kg = kz + kt*32;
        int seg = kg >> ksh;
        const float* sp = (seg==0)? A0 : ((seg==1)? A1 : A2);
        long ro = (seg==0)? ro0 : ro1;
        int ko = kg & ((1<<ksh)-1);
        const float* p = sp + ro + ko + q4*4;
        va0 = *(const float4*)p;
        va1 = *(const float4*)(p + 16);
        size_t wi = (size_t)(kg>>5)*((size_t)Nld*32) + wbase;
        vw0 = *(const uint4*)(Wh + wi);
        vw1 = *(const uint4*)(Wm + wi);
        vw2 = *(const uint4*)(Wl + wi);
    };
    auto commit = [&](int buf){
        uint2 H,M,L;
        splitw8(va0,H,M,L);
        *(uint2*)&sA[buf][0][b0 + p0s] = H;
        *(uint2*)&sA[buf][1][b0 + p0s] = M;
        *(uint2*)&sA[buf][2][b0 + p0s] = L;
        splitw8(va1,H,M,L);
        *(uint2*)&sA[buf][0][b0 + p1s] = H;
        *(uint2*)&sA[buf][1][b0 + p1s] = M;
        *(uint2*)&sA[buf][2][b0 + p1s] = L;
        *(uint4*)&sW[buf][0][tid*8] = vw0;
        *(uint4*)&sW[buf][1][tid*8] = vw1;
        *(uint4*)&sW[buf][2][tid*8] = vw2;
    };

    const int wid = tid >> 6, lane = tid & 63;
    const int wy = wid >> 1, wx = wid & 1;
    const int l15 = lane & 15, l4 = lane >> 4;
    const int offA = (wy*32 + l15)*32 + ((l4 ^ (l15&3))<<3);
    const int offB = (wx*32 + l15)*32 + ((l4 ^ (l15&3))<<3);

    auto compute = [&](int buf){
        short8 a0h = *(const short8*)&sA[buf][0][offA];
        short8 a0m = *(const short8*)&sA[buf][1][offA];
        short8 a0l = *(const short8*)&sA[buf][2][offA];
        short8 a1h = *(const short8*)&sA[buf][0][offA+512];
        short8 a1m = *(const short8*)&sA[buf][1][offA+512];
        short8 a1l = *(const short8*)&sA[buf][2][offA+512];
        short8 b0h = *(const short8*)&sW[buf][0][offB];
        short8 b0m = *(const short8*)&sW[buf][1][offB];
        short8 b0l = *(const short8*)&sW[buf][2][offB];
        short8 b1h = *(const short8*)&sW[buf][0][offB+512];
        short8 b1m = *(const short8*)&sW[buf][1][offB+512];
        short8 b1l = *(const short8*)&sW[buf][2][offB+512];
        MM6(a0h,a0m,a0l,b0h,b0m,b0l,acc[0][0])
        MM6(a0h,a0m,a0l,b1h,b1m,b1l,acc[0][1])
        MM6(a1h,a1m,a1l,b0h,b0m,b0l,acc[1][0])
        MM6(a1h,a1m,a1l,b1h,b1m,b1l,acc[1][1])
    };

    issue(0);
    commit(0);
    __syncthreads();
    int buf = 0;
    for (int kt=0; kt<nk; ++kt){
        bool more = (kt+1 < nk);
        if (more) issue(kt+1);
        compute(buf);
        if (more) commit(buf^1);
        __syncthreads();
        buf ^= 1;
    }

    if (MODE == 0){
        #pragma unroll
        for (int fa=0; fa<2; fa++){
            #pragma unroll
            for (int fb=0; fb<2; fb++){
                int gc = col0 + wx*32 + fb*16 + l15;
                float bv = bias ? bias[gc] : 0.0f;
                #pragma unroll
                for (int i=0;i<4;i++){
                    int r = row0 + wy*32 + fa*16 + l4*4 + i;
                    float v = acc[fa][fb][i] + bv;
                    if (relu) v = fmaxf(v, 0.0f);
                    out[(size_t)(r&255)*oB + (size_t)(r>>8)*oT + gc] = v;
                }
            }
        }
    } else if (MODE == 1){
        #pragma unroll
        for (int fa=0; fa<2; fa++){
            #pragma unroll
            for (int fb=0; fb<2; fb++){
                int gc = col0 + wx*32 + fb*16 + l15;
                #pragma unroll
                for (int i=0;i<4;i++){
                    int r = row0 + wy*32 + fa*16 + l4*4 + i;
                    out[((size_t)blockIdx.z*Mrows + r)*(size_t)Nld + gc] = acc[fa][fb][i];
                }
            }
        }
    } else {
        #pragma unroll
        for (int fa=0; fa<2; fa++){
            #pragma unroll
            for (int fb=0; fb<2; fb++){
                int gc = col0 + wx*32 + fb*16 + l15;
                int q = gc >> 2, g = gc & 3;
                #pragma unroll
                for (int i=0;i<4;i++){
                    int r = row0 + wy*32 + fa*16 + l4*4 + i;
                    float z = acc[fa][fb][i] + xz[(size_t)r*2048 + gc];
                    float x1 = __shfl_xor(z, 1);
                    float x2 = __shfl_xor(z, 2);
                    float x3 = __shfl_xor(z, 3);
                    float zi = (g==0)?z :(g==1)?x1:(g==2)?x2:x3;
                    float zf = (g==1)?z :(g==0)?x1:(g==3)?x2:x3;
                    float zg = (g==2)?z :(g==3)?x1:(g==0)?x2:x3;
                    float zo = (g==3)?z :(g==2)?x1:(g==1)?x2:x3;
                    float co = c_io[(size_t)r*512 + q];
                    float cn = sigf(zf)*co + sigf(zi)*tanh_f(zg);
                    float hn = sigf(zo)*tanh_f(cn);
                    if (g == 1) c_io[(size_t)r*512 + q] = cn;
                    else if (g == 0) seqo[(size_t)r*512 + q] = hn;
                }
            }
        }
    }
}

// ---------------- decoder LSTM cell over K-split partials ----------------
__global__ __launch_bounds__(256) void cell_red(
    const float* __restrict__ zp, int KS, const float* __restrict__ bias,
    float* __restrict__ c_io, float* __restrict__ h)
{
    int id = blockIdx.x*256 + threadIdx.x;   // 131072 = 256*512
    int b = id >> 9, q = id & 511;
    float4 z = *(const float4*)(zp + (size_t)b*2048 + q*4);
    for (int s=1; s<KS; s++){
        float4 t = *(const float4*)(zp + ((size_t)s*256 + b)*2048 + q*4);
        z.x += t.x; z.y += t.y; z.z += t.z; z.w += t.w;
    }
    float4 bb = *(const float4*)(bias + q*4);
    float zi = z.x + bb.x, zf = z.y + bb.y, zg = z.z + bb.z, zo = z.w + bb.w;
    float co = c_io[id];
    float cn = sigf(zf)*co + sigf(zi)*tanh_f(zg);
    float hn = sigf(zo)*tanh_f(cn);
    c_io[id] = cn;
    h[id] = hn;
}

// ---------------- generic reduce: bias + opt relu ----------------
__global__ __launch_bounds__(256) void red1(
    const float* __restrict__ zp, int KS, int ln, const float* __restrict__ bias,
    int relu, float* __restrict__ out)
{
    int id = blockIdx.x*256 + threadIdx.x;
    int b = id >> ln, n = id & ((1<<ln)-1);
    float v = 0.f;
    for (int s=0; s<KS; s++) v += zp[(((size_t)s*256 + b) << ln) + n];
    v += bias[n];
    if (relu) v = fmaxf(v, 0.f);
    out[id] = v;
}

// ---------------- fused attention (unchanged from round 1) ----------------
__global__ __launch_bounds__(256) void attn_kernel(
    const float* __restrict__ ht, const float* __restrict__ ot,
    const float* __restrict__ enc, const float* __restrict__ fc3,
    float* __restrict__ ctx)
{
    __shared__ float hts[256], f3s[256], wsm[SS];
    const int b = blockIdx.x, tid = threadIdx.x;
    hts[tid] = ht[(size_t)b*256 + tid];
    f3s[tid] = fc3[tid];
    __syncthreads();
    const int wave = tid >> 6, lane = tid & 63;
    const float* otb = ot + (size_t)b*SS*256;
    for (int i=0;i<32;i++){
        int s = wave*32 + i;
        float4 o = *(const float4*)&otb[(size_t)s*256 + lane*4];
        int d0 = lane*4;
        float v = f3s[d0+0]*tanh_f(o.x + hts[d0+0])
                + f3s[d0+1]*tanh_f(o.y + hts[d0+1])
                + f3s[d0+2]*tanh_f(o.z + hts[d0+2])
                + f3s[d0+3]*tanh_f(o.w + hts[d0+3]);
        #pragma unroll
        for (int off=32; off; off>>=1) v += __shfl_xor(v, off);
        if (lane == 0) wsm[s] = v;
    }
    __syncthreads();
    if (tid < 64){
        float v0 = wsm[tid], v1 = wsm[tid+64];
        float m = fmaxf(v0, v1);
        #pragma unroll
        for (int off=32; off; off>>=1) m = fmaxf(m, __shfl_xor(m, off));
        float e0 = __expf(v0 - m), e1 = __expf(v1 - m);
        float ss = e0 + e1;
        #pragma unroll
        for (int off=32; off; off>>=1) ss += __shfl_xor(ss, off);
        float inv = 1.0f/ss;
        wsm[tid] = e0*inv; wsm[tid+64] = e1*inv;
    }
    __syncthreads();
    float a0=0.f, a1=0.f;
    const float* eb = enc + (size_t)b*HH;
    #pragma unroll 8
    for (int s=0;s<SS;s++){
        float w = wsm[s];
        const float* e = eb + (size_t)s*BB*HH;
        a0 = fmaf(w, e[tid],      a0);
        a1 = fmaf(w, e[tid+256],  a1);
    }
    ctx[(size_t)b*HH + tid]      = a0;
    ctx[(size_t)b*HH + tid+256]  = a1;
}

__global__ __launch_bounds__(64) void argmax_kernel(const float* __restrict__ logits, int* __restrict__ tok){
    const int b = blockIdx.x, lane = threadIdx.x;
    const float* r = logits + (size_t)b*128;
    float v0 = r[lane], v1 = r[lane+64];
    float bv; int bi;
    if (v1 > v0){ bv = v1; bi = lane+64; } else { bv = v0; bi = lane; }
    #pragma unroll
    for (int off=32; off; off>>=1){
        float ov = __shfl_xor(bv, off);
        int   oi = __shfl_xor(bi, off);
        if (ov > bv || (ov == bv && oi < bi)){ bv = ov; bi = oi; }
    }
    if (lane == 0) tok[b] = bi;
}

extern "C" void kernel_launch(void* const* d_in, const int* in_sizes, int n_in,
                              void* d_out, int out_size, void* d_ws, size_t ws_size,
                              hipStream_t stream)
{
    (void)in_sizes; (void)n_in; (void)out_size;
    const float* l2      = (const float*)d_in[0];
    const float* e_wih[3] = {(const float*)d_in[1],(const float*)d_in[4],(const float*)d_in[7]};
    const float* e_whh[3] = {(const float*)d_in[2],(const float*)d_in[5],(const float*)d_in[8]};
    const float* e_b[3]   = {(const float*)d_in[3],(const float*)d_in[6],(const float*)d_in[9]};
    const float* d_wih[3] = {(const float*)d_in[10],(const float*)d_in[13],(const float*)d_in[16]};
    const float* d_whh[3] = {(const float*)d_in[11],(const float*)d_in[14],(const float*)d_in[17]};
    const float* d_b[3]   = {(const float*)d_in[12],(const float*)d_in[15],(const float*)d_in[18]};
    const float* emb   = (const float*)d_in[19];
    const float* fc1_w = (const float*)d_in[20]; const float* fc1_b = (const float*)d_in[21];
    const float* fc2_w = (const float*)d_in[22]; const float* fc2_b = (const float*)d_in[23];
    const float* fc3_w = (const float*)d_in[24];
    const float* w1 = (const float*)d_in[25]; const float* b1 = (const float*)d_in[26];
    const float* w2 = (const float*)d_in[27]; const float* b2 = (const float*)d_in[28];
    const float* w3 = (const float*)d_in[29]; const float* b3 = (const float*)d_in[30];
    float* out = (float*)d_out;

    float* base = (float*)d_ws;
    size_t off = 0;
    auto alloc = [&](size_t n)->float*{ float* r = base + off; off = (off + n + 63) & ~(size_t)63; return r; };

    // ---- weight plane table: {srcA, KA, srcB, KB, interleave, N} ----
    struct WSpec { const float* a; int ka; const float* b; int kb; int ilv; int n; };
    WSpec ws[14] = {
        {e_wih[0],128, nullptr,0, 1,2048}, {e_wih[1],512, nullptr,0, 1,2048}, {e_wih[2],512, nullptr,0, 1,2048},
        {e_whh[0],512, nullptr,0, 1,2048}, {e_whh[1],512, nullptr,0, 1,2048}, {e_whh[2],512, nullptr,0, 1,2048},
        {d_wih[0],1024, d_whh[0],512, 1,2048}, {d_wih[1],512, d_whh[1],512, 1,2048}, {d_wih[2],512, d_whh[2],512, 1,2048},
        {fc1_w,512, nullptr,0, 0,256}, {fc2_w,512, nullptr,0, 0,256},
        {w1,1024, nullptr,0, 0,512}, {w2,512, nullptr,0, 0,256}, {w3,256, nullptr,0, 0,128}
    };
    unsigned short* wp[14][3];
    for (int i=0;i<14;i++){
        size_t sz = (size_t)(ws[i].ka + ws[i].kb) * ws[i].n;          // ushorts per plane
        float* blk = alloc((sz*3 + 1)/2);
        wp[i][0] = (unsigned short*)blk;
        wp[i][1] = wp[i][0] + sz;
        wp[i][2] = wp[i][0] + 2*sz;
    }
    float* br_e[3]; for (int l=0;l<3;l++) br_e[l] = alloc(2048);
    float* br_d[3]; for (int l=0;l<3;l++) br_d[l] = alloc(2048);

    float* seq   = alloc((size_t)SS*BB*HH);      // encoder h sequence (fp32)
    float* ot    = alloc((size_t)BB*SS*256);     // [b][s][256]
    float* zpart = alloc((size_t)2*BB*H4);       // K-split partials (max 2x256x2048)
    float* zbuf  = alloc((size_t)BB*HH);
    float* cbuf[3]; for (int l=0;l<3;l++) cbuf[l] = alloc((size_t)BB*HH);
    float* hbuf[3]; for (int l=0;l<3;l++) hbuf[l] = alloc((size_t)BB*HH);
    float* ctx  = alloc((size_t)BB*HH);
    float* ht   = alloc((size_t)BB*256);
    float* hdd1 = alloc((size_t)BB*512);
    float* hdd2 = alloc((size_t)BB*256);
    int*   tok  = (int*)alloc(256);

    // xz chunk buffer from remaining workspace
    size_t remain = (ws_size/4 > off) ? (ws_size/4 - off) : 0;
    int CH = 4;
    if      (remain >= (size_t)32*BB*H4) CH = 32;
    else if (remain >= (size_t)16*BB*H4) CH = 16;
    else if (remain >= (size_t) 8*BB*H4) CH = 8;
    float* xz = base + off;

    // ---- build weight planes + biases ----
    for (int i=0;i<14;i++){
        int K = ws[i].ka + ws[i].kb;
        hipLaunchKernelGGL(split_w, dim3((K+127)/128, ws[i].n), dim3(128), 0, stream,
                           ws[i].a, ws[i].ka, ws[i].b, ws[i].kb, ws[i].ilv,
                           wp[i][0], wp[i][1], wp[i][2], ws[i].n);
    }
    for (int l=0;l<3;l++){
        hipLaunchKernelGGL(repack_b, dim3(8), dim3(256), 0, stream, br_e[l], e_b[l]);
        hipLaunchKernelGGL(repack_b, dim3(8), dim3(256), 0, stream, br_d[l], d_b[l]);
    }
    hipMemsetAsync(zbuf, 0, (size_t)BB*HH*4, stream);
    for (int l=0;l<3;l++) hipMemsetAsync(cbuf[l], 0, (size_t)BB*HH*4, stream);
    hipMemsetAsync(ctx, 0, (size_t)BB*HH*4, stream);

    // ---- encoder: chunked x-transform (MODE0) + sequential fused-cell steps (MODE2) ----
    for (int l=0;l<3;l++){
        const int Kih = (l==0)? FDIM : HH;
        const int wih = l, whhI = 3+l;
        const int nch = SS / CH;
        for (int tc=0; tc<nch; tc++){
            const float* A0; long sB, sT;
            if (l == 0){ A0 = l2 + (size_t)tc*CH*FDIM; sB = (long)SS*FDIM; sT = FDIM; }
            else       { A0 = seq + (size_t)tc*CH*BB*HH; sB = HH; sT = (long)BB*HH; }
            hipLaunchKernelGGL((mg<0>), dim3(32, CH*4, 1), dim3(256), 0, stream,
                A0, sB, sT, (const float*)nullptr, (const float*)nullptr, (const int*)nullptr, 30,
                wp[wih][0], wp[wih][1], wp[wih][2], 2048, Kih, 256,
                br_e[l], 0, xz, (long)H4, (long)BB*H4,
                (const float*)nullptr, (float*)nullptr, (float*)nullptr);
            for (int ti=0; ti<CH; ti++){
                int t = tc*CH + ti;
                const float* hp = (t==0) ? zbuf : seq + (size_t)(t-1)*BB*HH;
                hipLaunchKernelGGL((mg<2>), dim3(32, 4, 1), dim3(256), 0, stream,
                    hp, (long)HH, 0L, (const float*)nullptr, (const float*)nullptr, (const int*)nullptr, 30,
                    wp[whhI][0], wp[whhI][1], wp[whhI][2], 2048, HH, 256,
                    (const float*)nullptr, 0, (float*)nullptr, 0L, 0L,
                    xz + (size_t)ti*BB*H4, cbuf[l], seq + (size_t)t*BB*HH);
            }
        }
        hipMemcpyAsync(hbuf[l], seq + (size_t)(SS-1)*BB*HH, (size_t)BB*HH*4,
                       hipMemcpyDeviceToDevice, stream);
    }

    // ---- ot = enc_outs @ fc2^T + fc2_b  ([b][s][256]) ----
    hipLaunchKernelGGL((mg<0>), dim3(4, 512, 1), dim3(256), 0, stream,
        seq, (long)HH, (long)BB*HH, (const float*)nullptr, (const float*)nullptr, (const int*)nullptr, 30,
        wp[10][0], wp[10][1], wp[10][2], 256, HH, 256,
        fc2_b, 0, ot, (long)SS*256, 256L,
        (const float*)nullptr, (float*)nullptr, (float*)nullptr);

    // ---- decoder ----
    hipLaunchKernelGGL(init_tok, dim3(1), dim3(256), 0, stream, tok);
    for (int t=0; t<TDEC; t++){
        // L0: [emb[tok] | ctx | h0], K=1536, KS=2
        hipLaunchKernelGGL((mg<1>), dim3(32, 4, 2), dim3(256), 0, stream,
            emb, (long)HH, 0L, ctx, hbuf[0], tok, 9,
            wp[6][0], wp[6][1], wp[6][2], 2048, 768, 256,
            (const float*)nullptr, 0, zpart, 0L, 0L,
            (const float*)nullptr, (float*)nullptr, (float*)nullptr);
        hipLaunchKernelGGL(cell_red, dim3(512), dim3(256), 0, stream, zpart, 2, br_d[0], cbuf[0], hbuf[0]);
        // L1: [h0 | h1], K=1024, KS=2
        hipLaunchKernelGGL((mg<1>), dim3(32, 4, 2), dim3(256), 0, stream,
            hbuf[0], (long)HH, 0L, hbuf[1], (const float*)nullptr, (const int*)nullptr, 9,
            wp[7][0], wp[7][1], wp[7][2], 2048, 512, 256,
            (const float*)nullptr, 0, zpart, 0L, 0L,
            (const float*)nullptr, (float*)nullptr, (float*)nullptr);
        hipLaunchKernelGGL(cell_red, dim3(512), dim3(256), 0, stream, zpart, 2, br_d[1], cbuf[1], hbuf[1]);
        // L2
        hipLaunchKernelGGL((mg<1>), dim3(32, 4, 2), dim3(256), 0, stream,
            hbuf[1], (long)HH, 0L, hbuf[2], (const float*)nullptr, (const int*)nullptr, 9,
            wp[8][0], wp[8][1], wp[8][2], 2048, 512, 256,
            (const float*)nullptr, 0, zpart, 0L, 0L,
            (const float*)nullptr, (float*)nullptr, (float*)nullptr);
        hipLaunchKernelGGL(cell_red, dim3(512), dim3(256), 0, stream, zpart, 2, br_d[2], cbuf[2], hbuf[2]);
        // fc1: ht = h2 @ fc1^T + b  (direct)
        hipLaunchKernelGGL((mg<0>), dim3(4, 4, 1), dim3(256), 0, stream,
            hbuf[2], (long)HH, 0L, (const float*)nullptr, (const float*)nullptr, (const int*)nullptr, 30,
            wp[9][0], wp[9][1], wp[9][2], 256, HH, 256,
            fc1_b, 0, ht, 256L, 0L,
            (const float*)nullptr, (float*)nullptr, (float*)nullptr);
        // attention -> ctx
        hipLaunchKernelGGL(attn_kernel, dim3(BB), dim3(256), 0, stream, ht, ot, seq, fc3_w, ctx);
        // mlp1: [h2 | ctx] @ w1^T, K=1024, KS=4 -> relu -> hdd1
        hipLaunchKernelGGL((mg<1>), dim3(8, 4, 4), dim3(256), 0, stream,
            hbuf[2], (long)HH, 0L, ctx, (const float*)nullptr, (const int*)nullptr, 9,
            wp[11][0], wp[11][1], wp[11][2], 512, 256, 256,
            (const float*)nullptr, 0, zpart, 0L, 0L,
            (const float*)nullptr, (float*)nullptr, (float*)nullptr);
        hipLaunchKernelGGL(red1, dim3(512), dim3(256), 0, stream, zpart, 4, 9, b1, 1, hdd1);
        // mlp2: hdd1 @ w2^T, K=512, KS=4 -> relu -> hdd2
        hipLaunchKernelGGL((mg<1>), dim3(4, 4, 4), dim3(256), 0, stream,
            hdd1, 512L, 0L, (const float*)nullptr, (const float*)nullptr, (const int*)nullptr, 30,
            wp[12][0], wp[12][1], wp[12][2], 256, 128, 256,
            (const float*)nullptr, 0, zpart, 0L, 0L,
            (const float*)nullptr, (float*)nullptr, (float*)nullptr);
        hipLaunchKernelGGL(red1, dim3(256), dim3(256), 0, stream, zpart, 4, 8, b2, 1, hdd2);
        // mlp3: hdd2 @ w3^T + b3 (direct) -> logits
        hipLaunchKernelGGL((mg<0>), dim3(2, 4, 1), dim3(256), 0, stream,
            hdd2, 256L, 0L, (const float*)nullptr, (const float*)nullptr, (const int*)nullptr, 30,
            wp[13][0], wp[13][1], wp[13][2], 128, 256, 256,
            b3, 0, out + (size_t)t*BB*128, 128L, 0L,
            (const float*)nullptr, (float*)nullptr, (float*)nullptr);
        hipLaunchKernelGGL(argmax_kernel, dim3(BB), dim3(64), 0, stream, out + (size_t)t*BB*128, tok);
    }
}